// Round 3
// baseline (228.463 us; speedup 1.0000x reference)
//
#include <hip/hip_runtime.h>

typedef short bf16x8 __attribute__((ext_vector_type(8)));
typedef float f32x4 __attribute__((ext_vector_type(4)));
typedef unsigned short us4 __attribute__((ext_vector_type(4)));
typedef unsigned short us8 __attribute__((ext_vector_type(8)));

#define MFMA16(a, b, c) __builtin_amdgcn_mfma_f32_16x16x32_bf16(a, b, c, 0, 0, 0)

__device__ __forceinline__ unsigned short f2bf(float f) {
    unsigned int u = __float_as_uint(f);
    u += 0x7FFFu + ((u >> 16) & 1u);   // round-to-nearest-even
    return (unsigned short)(u >> 16);
}

// ---------------- workspace layout (bytes) ----------------
#define WQT_OFF 0          // ushort[576*192]  W_qkv^T bf16, Q rows pre-scaled
#define WOT_OFF 221184     // ushort[192*192]  W_out^T  bf16
#define BQ_OFF  294912     // float[576]       b_qkv, Q part pre-scaled
#define QWS_OFF 297216     // 2048 regions x 13312 B: Q [64][104] us (O overwrites)
#define KWS_OFF 27560192   // 2048 regions x 13312 B: K [64][104] us
#define VWS_OFF 54823168   // 2048 regions x 13312 B: Vt [96][68] us
// total 82,086,144 bytes
#define REGION 6656        // us per (bw,hh) region

// ================= prep: coalesced LDS-tiled weight transpose =================
__global__ void prep_kernel(const float* __restrict__ Wqkv,
                            const float* __restrict__ bqkv,
                            const float* __restrict__ Wout,
                            unsigned short* __restrict__ WqT,
                            unsigned short* __restrict__ WoT,
                            float* __restrict__ bq) {
    __shared__ float tile[32][33];
    const float SCALE = 0.17677669529663687f;  // 1/sqrt(32)
    int bid = blockIdx.x;
    int tx = threadIdx.x & 31, ty = threadIdx.x >> 5;
    if (bid < 108) {                       // W_qkv [192][576] -> WqT [576][192]
        int tn = bid % 18, tc = bid / 18;
#pragma unroll
        for (int i = 0; i < 4; ++i)
            tile[ty + i * 8][tx] = Wqkv[(tc * 32 + ty + i * 8) * 576 + tn * 32 + tx];
        __syncthreads();
        bool isQ = (tn < 6);
#pragma unroll
        for (int i = 0; i < 4; ++i) {
            float v = tile[tx][ty + i * 8];
            if (isQ) v *= SCALE;
            WqT[(tn * 32 + ty + i * 8) * 192 + tc * 32 + tx] = f2bf(v);
        }
    } else if (bid < 144) {                // W_out [192][192] -> WoT [192][192]
        int bb = bid - 108;
        int tn = bb % 6, tc = bb / 6;
#pragma unroll
        for (int i = 0; i < 4; ++i)
            tile[ty + i * 8][tx] = Wout[(tc * 32 + ty + i * 8) * 192 + tn * 32 + tx];
        __syncthreads();
#pragma unroll
        for (int i = 0; i < 4; ++i)
            WoT[(tn * 32 + ty + i * 8) * 192 + tc * 32 + tx] = f2bf(tile[tx][ty + i * 8]);
    } else {
        for (int i = threadIdx.x; i < 576; i += 256) {
            float v = bqkv[i];
            if (i < 192) v *= SCALE;
            bq[i] = v;
        }
    }
}

// ================= K_A: QKV GEMM per window, write Q/K/Vt to ws =================
__global__ __launch_bounds__(384) void qkv_kernel(
    const float* __restrict__ x,
    const unsigned short* __restrict__ WqT,
    const float* __restrict__ bq,
    unsigned short* __restrict__ Qws,
    unsigned short* __restrict__ Kws,
    unsigned short* __restrict__ Vws) {
    __shared__ __align__(16) unsigned short sX[64 * 200];
    const int tid = threadIdx.x;
    const int bw = blockIdx.x;
    const int b = bw >> 9, w = bw & 511;
    const int wz = w >> 6, wy = (w >> 3) & 7, wx = w & 7;

    // stage X window fp32 -> bf16 LDS (roll(-2) folded in)
#pragma unroll
    for (int p = 0; p < 4; ++p) {
        int f = p * 3072 + tid * 8;
        int t = f / 192, c = f - t * 192;
        int tz = t >> 4, ty = (t >> 2) & 3, tx = t & 3;
        int gz = (wz * 4 + tz + 2) & 31;
        int gy = (wy * 4 + ty + 2) & 31;
        int gx = (wx * 4 + tx + 2) & 31;
        const float* xp = x + ((((b * 32 + gz) * 32 + gy) * 32 + gx)) * 192 + c;
        float4 v0 = *(const float4*)xp;
        float4 v1 = *(const float4*)(xp + 4);
        us8 pk;
        pk[0] = f2bf(v0.x); pk[1] = f2bf(v0.y); pk[2] = f2bf(v0.z); pk[3] = f2bf(v0.w);
        pk[4] = f2bf(v1.x); pk[5] = f2bf(v1.y); pk[6] = f2bf(v1.z); pk[7] = f2bf(v1.w);
        *(us8*)&sX[t * 200 + c] = pk;
    }
    __syncthreads();

    const int lane = tid & 63;
    const int wv   = tid >> 6;     // 0..5
    const int g    = lane >> 4;
    const int l15  = lane & 15;

    bf16x8 afr[4][6];
#pragma unroll
    for (int m = 0; m < 4; ++m)
#pragma unroll
        for (int kk = 0; kk < 6; ++kk)
            afr[m][kk] = *(const bf16x8*)&sX[(m * 16 + l15) * 200 + kk * 32 + g * 8];

    int nb = wv;
    float bias = bq[nb * 16 + l15];
    bf16x8 bfr[6];
    {
        const unsigned short* wp = WqT + (nb * 16 + l15) * 192 + g * 8;
#pragma unroll
        for (int kk = 0; kk < 6; ++kk) bfr[kk] = *(const bf16x8*)(wp + kk * 32);
    }
    while (true) {
        int nbN = nb + 6;
        bool more = (nbN < 36);
        bf16x8 bfrN[6];
        float biasN = 0.f;
        if (more) {
            biasN = bq[nbN * 16 + l15];
            const unsigned short* wp = WqT + (nbN * 16 + l15) * 192 + g * 8;
#pragma unroll
            for (int kk = 0; kk < 6; ++kk) bfrN[kk] = *(const bf16x8*)(wp + kk * 32);
        }
#pragma unroll
        for (int m = 0; m < 4; ++m) {
            f32x4 acc = {bias, bias, bias, bias};
#pragma unroll
            for (int kk = 0; kk < 6; ++kk) acc = MFMA16(afr[m][kk], bfr[kk], acc);
            int row0 = m * 16 + g * 4;
            if (nb < 12) {                       // Q -> Qws[t][c96], stride 104
                int hh = nb / 6, c96 = (nb % 6) * 16 + l15;
                unsigned short* dst = Qws + (bw * 2 + hh) * REGION + c96;
#pragma unroll
                for (int r = 0; r < 4; ++r) dst[(row0 + r) * 104] = f2bf(acc[r]);
            } else if (nb < 24) {                // K -> Kws[t][c96], stride 104
                int kb = nb - 12;
                int hh = kb / 6, c96 = (kb % 6) * 16 + l15;
                unsigned short* dst = Kws + (bw * 2 + hh) * REGION + c96;
#pragma unroll
                for (int r = 0; r < 4; ++r) dst[(row0 + r) * 104] = f2bf(acc[r]);
            } else {                             // V -> Vws[c96][t], stride 68
                int vb = nb - 24;
                int hh = vb / 6, c96 = (vb % 6) * 16 + l15;
                us4 pk;
#pragma unroll
                for (int r = 0; r < 4; ++r) pk[r] = f2bf(acc[r]);
                *(us4*)&Vws[(bw * 2 + hh) * REGION + c96 * 68 + row0] = pk;
            }
        }
        if (!more) break;
        nb = nbN;
        bias = biasN;
#pragma unroll
        for (int kk = 0; kk < 6; ++kk) bfr[kk] = bfrN[kk];
    }
}

// ================= K_B: attention per (window, head-half) =================
// LDS (ushort idx): sQ@0 [64][104] | sK@6656 [64][104] | sVt@13312 [96][68]
//                   sP@19968 per-wave [16][72] | sRel(float)@26880
#define AQ 0
#define AK 6656
#define AV 13312
#define AP 19968
#define AREL 26880
#define ATTN_US 28938      // 57876 B

__global__ __launch_bounds__(384) void attn_kernel(
    const unsigned short* __restrict__ Qws,
    const unsigned short* __restrict__ Kws,
    const unsigned short* __restrict__ Vws,
    const float* __restrict__ rel,
    unsigned short* __restrict__ Ows) {          // == Qws regions, overwritten
    __shared__ __align__(16) unsigned short smem[ATTN_US];
    float* sRel = (float*)&smem[AREL];
    const int tid = threadIdx.x;
    const int bid = blockIdx.x;                  // bw*2 + hh
    const int hh = bid & 1;
    const int w = (bid >> 1) & 511;
    const int wz = w >> 6, wy = (w >> 3) & 7, wx = w & 7;

    for (int i = tid; i < 832; i += 384) {
        *(us8*)&smem[AQ + i * 8] = *(const us8*)&Qws[bid * REGION + i * 8];
        *(us8*)&smem[AK + i * 8] = *(const us8*)&Kws[bid * REGION + i * 8];
        *(us8*)&smem[AV + i * 8] = *(const us8*)&Vws[bid * REGION + i * 8];
    }
    for (int i = tid; i < 1029; i += 384) sRel[i] = rel[hh * 1029 + i];
    __syncthreads();

    const int lane = tid & 63;
    const int wv   = tid >> 6;
    const int g    = lane >> 4;
    const int l15  = lane & 15;
    const bool sz = (wz == 7), sy = (wy == 7), sx = (wx == 7);
    const int qy = (l15 >> 2) & 3, qx = l15 & 3;
    unsigned short* pb = &smem[AP + wv * 1152];

#pragma unroll
    for (int ii = 0; ii < 2; ++ii) {
        int it = wv * 2 + ii;
        int h3 = it >> 2, mb = it & 3;
        bf16x8 qf = *(const bf16x8*)&smem[AQ + (mb * 16 + l15) * 104 + h3 * 32 + g * 8];
        f32x4 s[4];
#pragma unroll
        for (int f = 0; f < 4; ++f) {
            bf16x8 kf = *(const bf16x8*)&smem[AK + (f * 16 + l15) * 104 + h3 * 32 + g * 8];
            f32x4 z = {0.f, 0.f, 0.f, 0.f};
            s[f] = MFMA16(qf, kf, z);
        }
#pragma unroll
        for (int f = 0; f < 4; ++f) {
            bool mz = sz && ((mb < 2) != (f < 2));
            bool my = sy && ((g < 2) != (qy < 2));
            int base = h3 * 343 + (mb - f + 3) * 49 + (g - qy + 3) * 7 + (3 - qx);
#pragma unroll
            for (int r = 0; r < 4; ++r) {
                float v = s[f][r] + sRel[base + r];
                bool mx = sx && ((r < 2) != (qx < 2));
                s[f][r] = (mz | my | mx) ? -1e30f : v;
            }
        }
#pragma unroll
        for (int r = 0; r < 4; ++r) {
            float m0 = fmaxf(fmaxf(s[0][r], s[1][r]), fmaxf(s[2][r], s[3][r]));
#pragma unroll
            for (int d = 1; d < 16; d <<= 1) m0 = fmaxf(m0, __shfl_xor(m0, d, 64));
            float p0 = __expf(s[0][r] - m0);
            float p1 = __expf(s[1][r] - m0);
            float p2 = __expf(s[2][r] - m0);
            float p3 = __expf(s[3][r] - m0);
            float sm = p0 + p1 + p2 + p3;
#pragma unroll
            for (int d = 1; d < 16; d <<= 1) sm += __shfl_xor(sm, d, 64);
            float inv = 1.0f / sm;
            s[0][r] = p0 * inv; s[1][r] = p1 * inv;
            s[2][r] = p2 * inv; s[3][r] = p3 * inv;
        }
#pragma unroll
        for (int f = 0; f < 4; ++f)
#pragma unroll
            for (int r = 0; r < 4; ++r)
                pb[(g * 4 + r) * 72 + f * 16 + l15] = f2bf(s[f][r]);
        f32x4 o0 = {0.f, 0.f, 0.f, 0.f}, o1 = {0.f, 0.f, 0.f, 0.f};
#pragma unroll
        for (int kt = 0; kt < 2; ++kt) {
            bf16x8 pf = *(const bf16x8*)&pb[l15 * 72 + kt * 32 + g * 8];
            bf16x8 v0 = *(const bf16x8*)&smem[AV + (h3 * 32 + l15) * 68 + kt * 32 + g * 8];
            bf16x8 v1 = *(const bf16x8*)&smem[AV + (h3 * 32 + 16 + l15) * 68 + kt * 32 + g * 8];
            o0 = MFMA16(pf, v0, o0);
            o1 = MFMA16(pf, v1, o1);
        }
        // O tile (16x32) -> per-wave scratch -> coalesced us8 store over Q region
#pragma unroll
        for (int r = 0; r < 4; ++r) {
            pb[(g * 4 + r) * 32 + l15]      = f2bf(o0[r]);
            pb[(g * 4 + r) * 32 + 16 + l15] = f2bf(o1[r]);
        }
        us8 pk = *(const us8*)&pb[(lane >> 2) * 32 + (lane & 3) * 8];
        *(us8*)&Ows[bid * REGION + (mb * 16 + (lane >> 2)) * 104 + h3 * 32 + (lane & 3) * 8] = pk;
    }
}

// ================= K_C: out = O @ WoutT^T + b_out, un-window + roll =================
__global__ __launch_bounds__(256) void oproj_kernel(
    const unsigned short* __restrict__ Ows,
    const unsigned short* __restrict__ WoT,
    const float* __restrict__ bout, float* __restrict__ out) {
    const int bw = blockIdx.x;
    const int b  = bw >> 9;
    const int w  = bw & 511;
    const int wz = w >> 6, wy = (w >> 3) & 7, wx = w & 7;
    const int lane = threadIdx.x & 63;
    const int wv   = threadIdx.x >> 6;     // m-block 0..3
    const int g    = lane >> 4;
    const int l15  = lane & 15;

    bf16x8 af[6];
#pragma unroll
    for (int kk = 0; kk < 6; ++kk) {
        int hh = (kk >= 3) ? 1 : 0;
        af[kk] = *(const bf16x8*)&Ows[(bw * 2 + hh) * REGION + (wv * 16 + l15) * 104 + (kk - hh * 3) * 32 + g * 8];
    }
    const int gz = (wz * 4 + wv + 2) & 31;   // roll(+2)
    const int gy = (wy * 4 + g + 2) & 31;
#pragma unroll
    for (int nb = 0; nb < 12; ++nb) {
        float bo = bout[nb * 16 + l15];
        const unsigned short* wp = WoT + (nb * 16 + l15) * 192 + g * 8;
        bf16x8 bf[6];
#pragma unroll
        for (int kk = 0; kk < 6; ++kk) bf[kk] = *(const bf16x8*)(wp + kk * 32);
        f32x4 acc = {bo, bo, bo, bo};
#pragma unroll
        for (int kk = 0; kk < 6; ++kk) acc = MFMA16(af[kk], bf[kk], acc);
        int col = nb * 16 + l15;
#pragma unroll
        for (int r = 0; r < 4; ++r) {
            int gx = (wx * 4 + r + 2) & 31;
            out[(((b * 32 + gz) * 32 + gy) * 32 + gx) * 192 + col] = acc[r];
        }
    }
}

extern "C" void kernel_launch(void* const* d_in, const int* in_sizes, int n_in,
                              void* d_out, int out_size, void* d_ws, size_t ws_size,
                              hipStream_t stream) {
    const float* x    = (const float*)d_in[0];
    const float* Wqkv = (const float*)d_in[1];
    const float* bqkv = (const float*)d_in[2];
    const float* rel  = (const float*)d_in[3];
    const float* Wout = (const float*)d_in[4];
    const float* bout = (const float*)d_in[5];

    unsigned short* WqT = (unsigned short*)((char*)d_ws + WQT_OFF);
    unsigned short* WoT = (unsigned short*)((char*)d_ws + WOT_OFF);
    float*          bq  = (float*)((char*)d_ws + BQ_OFF);
    unsigned short* Qws = (unsigned short*)((char*)d_ws + QWS_OFF);
    unsigned short* Kws = (unsigned short*)((char*)d_ws + KWS_OFF);
    unsigned short* Vws = (unsigned short*)((char*)d_ws + VWS_OFF);
    float*          out = (float*)d_out;

    prep_kernel<<<145, 256, 0, stream>>>(Wqkv, bqkv, Wout, WqT, WoT, bq);
    qkv_kernel<<<1024, 384, 0, stream>>>(x, WqT, bq, Qws, Kws, Vws);
    attn_kernel<<<2048, 384, 0, stream>>>(Qws, Kws, Vws, rel, Qws);
    oproj_kernel<<<1024, 256, 0, stream>>>(Qws, WoT, bout, out);
}

// Round 4
// 205.848 us; speedup vs baseline: 1.1099x; 1.1099x over previous
//
#include <hip/hip_runtime.h>

typedef short bf16x8 __attribute__((ext_vector_type(8)));
typedef float f32x4 __attribute__((ext_vector_type(4)));
typedef unsigned short us4 __attribute__((ext_vector_type(4)));
typedef unsigned short us8 __attribute__((ext_vector_type(8)));

#define MFMA16(a, b, c) __builtin_amdgcn_mfma_f32_16x16x32_bf16(a, b, c, 0, 0, 0)

__device__ __forceinline__ unsigned short f2bf(float f) {
    unsigned int u = __float_as_uint(f);
    u += 0x7FFFu + ((u >> 16) & 1u);   // round-to-nearest-even
    return (unsigned short)(u >> 16);
}

// ---------------- workspace layout (bytes) ----------------
#define WQT_OFF 0         // ushort[576*192]  W_qkv^T bf16, Q rows pre-scaled
#define WOT_OFF 221184    // ushort[192*192]  W_out^T  bf16
#define BQ_OFF  294912    // float[576]       b_qkv, Q part pre-scaled
// total 297216 bytes

// ================= prep: coalesced LDS-tiled weight transpose =================
__global__ void prep_kernel(const float* __restrict__ Wqkv,
                            const float* __restrict__ bqkv,
                            const float* __restrict__ Wout,
                            unsigned short* __restrict__ WqT,
                            unsigned short* __restrict__ WoT,
                            float* __restrict__ bq) {
    __shared__ float tile[32][33];
    const float SCALE = 0.17677669529663687f;  // 1/sqrt(32)
    int bid = blockIdx.x;
    int tx = threadIdx.x & 31, ty = threadIdx.x >> 5;
    if (bid < 108) {                       // W_qkv [192][576] -> WqT [576][192]
        int tn = bid % 18, tc = bid / 18;
#pragma unroll
        for (int i = 0; i < 4; ++i)
            tile[ty + i * 8][tx] = Wqkv[(tc * 32 + ty + i * 8) * 576 + tn * 32 + tx];
        __syncthreads();
        bool isQ = (tn < 6);
#pragma unroll
        for (int i = 0; i < 4; ++i) {
            float v = tile[tx][ty + i * 8];
            if (isQ) v *= SCALE;
            WqT[(tn * 32 + ty + i * 8) * 192 + tc * 32 + tx] = f2bf(v);
        }
    } else if (bid < 144) {                // W_out [192][192] -> WoT [192][192]
        int bb = bid - 108;
        int tn = bb % 6, tc = bb / 6;
#pragma unroll
        for (int i = 0; i < 4; ++i)
            tile[ty + i * 8][tx] = Wout[(tc * 32 + ty + i * 8) * 192 + tn * 32 + tx];
        __syncthreads();
#pragma unroll
        for (int i = 0; i < 4; ++i)
            WoT[(tn * 32 + ty + i * 8) * 192 + tc * 32 + tx] = f2bf(tile[tx][ty + i * 8]);
    } else {
        for (int i = threadIdx.x; i < 576; i += 256) {
            float v = bqkv[i];
            if (i < 192) v *= SCALE;
            bq[i] = v;
        }
    }
}

// ---------------- fused kernel LDS layout (ushort units) ----------------
// sX  [64][200] bf16 window input; aliased by sO after phase 1
// sQK [64][392] bf16: Q cols 0..191 | K cols 192..383
// sVt [192][72] bf16 V transposed [c][t]
// sP  16 waves x [16][72] bf16 per-wave P transpose scratch
// sRel float[2058]
#define OFF_X    0
#define OFF_O    0
#define OFF_QK   12800
#define OFF_VT   37888
#define OFF_P    51712
#define OFF_RELF 70144     // float region (ushort index)
#define SMEM_US  74260     // 148520 bytes -> 1 block/CU, 16 waves

__global__ __launch_bounds__(1024) void wmsa_kernel(
    const float* __restrict__ x, const float* __restrict__ rel,
    const float* __restrict__ bout,
    const unsigned short* __restrict__ WqT,
    const unsigned short* __restrict__ WoT,
    const float* __restrict__ bq, float* __restrict__ out) {
    __shared__ __align__(16) unsigned short smem[SMEM_US];
    float* sRel = (float*)&smem[OFF_RELF];

    const int tid = threadIdx.x;
    const int bw = blockIdx.x;
    const int b  = bw >> 9;
    const int w  = bw & 511;
    const int wz = w >> 6, wy = (w >> 3) & 7, wx = w & 7;

    // ---------- phase 0: rel + x window (fp32 -> bf16 LDS), roll(-2) folded ----------
    {
        int t = tid >> 4, q16 = tid & 15;       // 16 threads per token
        int tz = t >> 4, ty = (t >> 2) & 3, tx = t & 3;
        int gz = (wz * 4 + tz + 2) & 31;
        int gy = (wy * 4 + ty + 2) & 31;
        int gx = (wx * 4 + tx + 2) & 31;
        const float* xp = x + ((((b * 32 + gz) * 32 + gy) * 32 + gx)) * 192;
#pragma unroll
        for (int k = 0; k < 3; ++k) {
            int c = (q16 << 2) + (k << 6);      // threads 0..15 cover 256B contiguous
            float4 v = *(const float4*)(xp + c);
            us4 pk;
            pk[0] = f2bf(v.x); pk[1] = f2bf(v.y);
            pk[2] = f2bf(v.z); pk[3] = f2bf(v.w);
            *(us4*)&smem[OFF_X + t * 200 + c] = pk;
        }
    }
    for (int i = tid; i < 2058; i += 1024) sRel[i] = rel[i];
    __syncthreads();

    const int lane = tid & 63;
    const int wv   = tid >> 6;     // wave id 0..15
    const int g    = lane >> 4;    // quad 0..3
    const int l15  = lane & 15;

    // ---------- phase 1: QKV = Xw(64x192) @ WqT^T -> 64x576 ----------
    // unit = (nb, m-half). wave wv: mh = wv&1 (m in {2mh,2mh+1}), nb = (wv>>1)+8j
    {
        const int mh = wv & 1;
        bf16x8 afr[2][6];
#pragma unroll
        for (int mi = 0; mi < 2; ++mi)
#pragma unroll
            for (int kk = 0; kk < 6; ++kk)
                afr[mi][kk] = *(const bf16x8*)&smem[OFF_X + ((2 * mh + mi) * 16 + l15) * 200 + kk * 32 + g * 8];

        for (int nb = wv >> 1; nb < 36; nb += 8) {
            float bias = bq[nb * 16 + l15];
            bf16x8 bfr[6];
            const unsigned short* wp = WqT + (nb * 16 + l15) * 192 + g * 8;
#pragma unroll
            for (int kk = 0; kk < 6; ++kk) bfr[kk] = *(const bf16x8*)(wp + kk * 32);
#pragma unroll
            for (int mi = 0; mi < 2; ++mi) {
                f32x4 acc = {bias, bias, bias, bias};
#pragma unroll
                for (int kk = 0; kk < 6; ++kk) acc = MFMA16(afr[mi][kk], bfr[kk], acc);
                int row0 = (2 * mh + mi) * 16 + g * 4;
                if (nb < 24) {                 // Q (cols 0..191) | K (cols 192..383)
                    int colg = ((nb < 12) ? nb * 16 : 192 + (nb - 12) * 16) + l15;
#pragma unroll
                    for (int r = 0; r < 4; ++r)
                        smem[OFF_QK + (row0 + r) * 392 + colg] = f2bf(acc[r]);
                } else {                       // V -> sVt[c][t]
                    int cl = (nb - 24) * 16 + l15;
                    us4 pk;
#pragma unroll
                    for (int r = 0; r < 4; ++r) pk[r] = f2bf(acc[r]);
                    *(us4*)&smem[OFF_VT + cl * 72 + row0] = pk;
                }
            }
        }
    }
    __syncthreads();

    // ---------- phase 2: attention, 24 units (6 heads x 4 mb) over 16 waves ----------
    const bool sz = (wz == 7), sy = (wy == 7), sx = (wx == 7);
    {
        const int qy = (l15 >> 2) & 3, qx = l15 & 3;
        unsigned short* pb = &smem[OFF_P + wv * 1152];
        for (int it = wv; it < 24; it += 16) {
            int h = it >> 2, mb = it & 3;
            bf16x8 qf = *(const bf16x8*)&smem[OFF_QK + (mb * 16 + l15) * 392 + h * 32 + g * 8];
            f32x4 s[4];
#pragma unroll
            for (int f = 0; f < 4; ++f) {
                bf16x8 kf = *(const bf16x8*)&smem[OFF_QK + (f * 16 + l15) * 392 + 192 + h * 32 + g * 8];
                f32x4 z = {0.f, 0.f, 0.f, 0.f};
                s[f] = MFMA16(qf, kf, z);
            }
            // bias + shift mask.  p=(mb,g,r), q=(f,qy,qx)
#pragma unroll
            for (int f = 0; f < 4; ++f) {
                bool mz = sz && ((mb < 2) != (f < 2));
                bool my = sy && ((g < 2) != (qy < 2));
                int base = h * 343 + (mb - f + 3) * 49 + (g - qy + 3) * 7 + (3 - qx);
#pragma unroll
                for (int r = 0; r < 4; ++r) {
                    float v = s[f][r] + sRel[base + r];
                    bool mx = sx && ((r < 2) != (qx < 2));
                    s[f][r] = (mz | my | mx) ? -1e30f : v;
                }
            }
            // softmax per row (row = mb*16 + g*4 + r)
#pragma unroll
            for (int r = 0; r < 4; ++r) {
                float m0 = fmaxf(fmaxf(s[0][r], s[1][r]), fmaxf(s[2][r], s[3][r]));
#pragma unroll
                for (int d = 1; d < 16; d <<= 1) m0 = fmaxf(m0, __shfl_xor(m0, d, 64));
                float p0 = __expf(s[0][r] - m0);
                float p1 = __expf(s[1][r] - m0);
                float p2 = __expf(s[2][r] - m0);
                float p3 = __expf(s[3][r] - m0);
                float sm = p0 + p1 + p2 + p3;
#pragma unroll
                for (int d = 1; d < 16; d <<= 1) sm += __shfl_xor(sm, d, 64);
                float inv = 1.0f / sm;
                s[0][r] = p0 * inv; s[1][r] = p1 * inv;
                s[2][r] = p2 * inv; s[3][r] = p3 * inv;
            }
            // P (C-layout) -> per-wave LDS scratch -> A-frags (same wave, no barrier)
#pragma unroll
            for (int f = 0; f < 4; ++f)
#pragma unroll
                for (int r = 0; r < 4; ++r)
                    pb[(g * 4 + r) * 72 + f * 16 + l15] = f2bf(s[f][r]);
            // PV: O(16x32) = P(16x64) @ V(64x32)
            f32x4 o0 = {0.f, 0.f, 0.f, 0.f}, o1 = {0.f, 0.f, 0.f, 0.f};
#pragma unroll
            for (int kt = 0; kt < 2; ++kt) {
                bf16x8 pf = *(const bf16x8*)&pb[l15 * 72 + kt * 32 + g * 8];
                bf16x8 v0 = *(const bf16x8*)&smem[OFF_VT + (h * 32 + l15) * 72 + kt * 32 + g * 8];
                bf16x8 v1 = *(const bf16x8*)&smem[OFF_VT + (h * 32 + 16 + l15) * 72 + kt * 32 + g * 8];
                o0 = MFMA16(pf, v0, o0);
                o1 = MFMA16(pf, v1, o1);
            }
#pragma unroll
            for (int r = 0; r < 4; ++r) {
                smem[OFF_O + (mb * 16 + g * 4 + r) * 200 + h * 32 + l15]      = f2bf(o0[r]);
                smem[OFF_O + (mb * 16 + g * 4 + r) * 200 + h * 32 + 16 + l15] = f2bf(o1[r]);
            }
        }
    }
    __syncthreads();

    // ---------- phase 3: out = O(64x192) @ WoT^T + b_out, 48 units = 3/wave ----------
    {
        const int m  = wv & 3;          // m-block (token z-slab)
        const int nb0 = wv >> 2;        // first n-block
        bf16x8 ofr[6];
#pragma unroll
        for (int kk = 0; kk < 6; ++kk)
            ofr[kk] = *(const bf16x8*)&smem[OFF_O + (m * 16 + l15) * 200 + kk * 32 + g * 8];
        const int gz = (wz * 4 + m + 2) & 31;   // roll(+2) folded in
        const int gy = (wy * 4 + g + 2) & 31;
#pragma unroll
        for (int j = 0; j < 3; ++j) {
            int nb = nb0 + j * 4;
            int col = nb * 16 + l15;
            float bo = bout[col];
            bf16x8 bfr[6];
            const unsigned short* wp = WoT + col * 192 + g * 8;
#pragma unroll
            for (int kk = 0; kk < 6; ++kk) bfr[kk] = *(const bf16x8*)(wp + kk * 32);
            f32x4 acc = {bo, bo, bo, bo};
#pragma unroll
            for (int kk = 0; kk < 6; ++kk) acc = MFMA16(ofr[kk], bfr[kk], acc);
#pragma unroll
            for (int r = 0; r < 4; ++r) {
                int gx = (wx * 4 + r + 2) & 31;
                out[(((b * 32 + gz) * 32 + gy) * 32 + gx) * 192 + col] = acc[r];
            }
        }
    }
}

extern "C" void kernel_launch(void* const* d_in, const int* in_sizes, int n_in,
                              void* d_out, int out_size, void* d_ws, size_t ws_size,
                              hipStream_t stream) {
    const float* x    = (const float*)d_in[0];
    const float* Wqkv = (const float*)d_in[1];
    const float* bqkv = (const float*)d_in[2];
    const float* rel  = (const float*)d_in[3];
    const float* Wout = (const float*)d_in[4];
    const float* bout = (const float*)d_in[5];

    unsigned short* WqT = (unsigned short*)((char*)d_ws + WQT_OFF);
    unsigned short* WoT = (unsigned short*)((char*)d_ws + WOT_OFF);
    float*          bq  = (float*)((char*)d_ws + BQ_OFF);
    float*          out = (float*)d_out;

    prep_kernel<<<145, 256, 0, stream>>>(Wqkv, bqkv, Wout, WqT, WoT, bq);
    wmsa_kernel<<<1024, 1024, 0, stream>>>(x, rel, bout, WqT, WoT, bq, out);
}

// Round 6
// 166.721 us; speedup vs baseline: 1.3703x; 1.2347x over previous
//
#include <hip/hip_runtime.h>

typedef short bf16x8 __attribute__((ext_vector_type(8)));
typedef float f32x4 __attribute__((ext_vector_type(4)));

#define MFMA16(a, b, c) __builtin_amdgcn_mfma_f32_16x16x32_bf16(a, b, c, 0, 0, 0)

__device__ __forceinline__ unsigned short f2bf(float f) {
    unsigned int u = __float_as_uint(f);
    u += 0x7FFFu + ((u >> 16) & 1u);   // round-to-nearest-even
    return (unsigned short)(u >> 16);
}
// packed pair: low16 = bf16(a), high16 = bf16(b)
__device__ __forceinline__ unsigned int f2bf2(float a, float b) {
    unsigned int ua = __float_as_uint(a);
    ua += 0x7FFFu + ((ua >> 16) & 1u);
    unsigned int ub = __float_as_uint(b);
    ub += 0x7FFFu + ((ub >> 16) & 1u);
    return (ua >> 16) | (ub & 0xFFFF0000u);
}
// add value from DPP-selected lane (16-lane row ops); all lanes active here
#define DPPADD(v, CTRL)                                                        \
    {                                                                          \
        int _t = __builtin_amdgcn_mov_dpp(__float_as_int(v), CTRL, 0xf, 0xf, true); \
        v += __int_as_float(_t);                                               \
    }

// ---------------- workspace layout (bytes) ----------------
#define WQT_OFF 0        // ushort[576*192]  W_qkv^T bf16, Q rows pre-scaled by scale*log2e
#define WOT_OFF 221184   // ushort[192*192]  W_out^T  bf16
#define BQ_OFF  294912   // float[576]       b_qkv, Q part pre-scaled
// total 297216 bytes

// ================= prep: coalesced LDS-tiled weight transpose =================
__global__ void prep_kernel(const float* __restrict__ Wqkv,
                            const float* __restrict__ bqkv,
                            const float* __restrict__ Wout,
                            unsigned short* __restrict__ WqT,
                            unsigned short* __restrict__ WoT,
                            float* __restrict__ bq) {
    __shared__ float tile[32][33];
    // 1/sqrt(32) * log2(e): softmax done in exp2 domain
    const float SCALE = 0.17677669529663687f * 1.4426950408889634f;
    int bid = blockIdx.x;
    int tx = threadIdx.x & 31, ty = threadIdx.x >> 5;
    if (bid < 108) {                       // W_qkv [192][576] -> WqT [576][192]
        int tn = bid % 18, tc = bid / 18;
#pragma unroll
        for (int i = 0; i < 4; ++i)
            tile[ty + i * 8][tx] = Wqkv[(tc * 32 + ty + i * 8) * 576 + tn * 32 + tx];
        __syncthreads();
        bool isQ = (tn < 6);
#pragma unroll
        for (int i = 0; i < 4; ++i) {
            float v = tile[tx][ty + i * 8];
            if (isQ) v *= SCALE;
            WqT[(tn * 32 + ty + i * 8) * 192 + tc * 32 + tx] = f2bf(v);
        }
    } else if (bid < 144) {                // W_out [192][192] -> WoT [192][192]
        int bb = bid - 108;
        int tn = bb % 6, tc = bb / 6;
#pragma unroll
        for (int i = 0; i < 4; ++i)
            tile[ty + i * 8][tx] = Wout[(tc * 32 + ty + i * 8) * 192 + tn * 32 + tx];
        __syncthreads();
#pragma unroll
        for (int i = 0; i < 4; ++i)
            WoT[(tn * 32 + ty + i * 8) * 192 + tc * 32 + tx] = f2bf(tile[tx][ty + i * 8]);
    } else {
        for (int i = threadIdx.x; i < 576; i += 256) {
            float v = bqkv[i];
            if (i < 192) v *= SCALE;
            bq[i] = v;
        }
    }
}

// ---------------- LDS layout (ushort units) ----------------
// sX  [64][208] bf16 window input (aliased by per-wave P scratch in phase 2)
// sQK [64][392] bf16 Q(cols 0..191, pre-scaled) | K(192..383)
// sVt [192][72] bf16 V transposed [c][t]
// sO  [64][208] bf16 attention output
// sRel float[2058] rel_params copy (pre-scaled by log2e)
#define OFF_X   0
#define OFF_P   0          // per-wave [16][72], aliases sX (dead after phase 1)
#define OFF_QK  13312
#define OFF_VT  38400
#define OFF_O   52224
#define OFF_RELF 65536     // float region starts here (ushort index)
#define SMEM_US 69652      // 139304 bytes

__global__ __launch_bounds__(512) void wmsa_kernel(
    const float* __restrict__ x, const float* __restrict__ rel,
    const float* __restrict__ bout,
    const unsigned short* __restrict__ WqT,
    const unsigned short* __restrict__ WoT,
    const float* __restrict__ bq, float* __restrict__ out) {
    __shared__ __align__(16) unsigned short smem[SMEM_US];
    float* sRel = (float*)&smem[OFF_RELF];

    const int tid = threadIdx.x;
    const int bw = blockIdx.x;
    const int b  = bw >> 9;
    const int w  = bw & 511;
    const int wz = w >> 6, wy = (w >> 3) & 7, wx = w & 7;

    const int lane = tid & 63;
    const int wv   = tid >> 6;     // wave id 0..7
    const int g    = lane >> 4;    // quad id 0..3
    const int l15  = lane & 15;

    // ---------- phase 0: load rel (log2-scaled) + x window (fp32 -> bf16 LDS) ----------
    for (int i = tid; i < 2058; i += 512) sRel[i] = rel[i] * 1.4426950408889634f;
    {
        int t = tid >> 3, q8 = tid & 7;           // 8 threads per token
        int tz = t >> 4, ty = (t >> 2) & 3, tx = t & 3;
        int gz = (wz * 4 + tz + 2) & 31;          // roll(-2) folded in
        int gy = (wy * 4 + ty + 2) & 31;
        int gx = (wx * 4 + tx + 2) & 31;
        const float* xp = x + ((((b * 32 + gz) * 32 + gy) * 32 + gx)) * 192;
#pragma unroll
        for (int k = 0; k < 6; ++k) {
            int c = (q8 << 2) + (k << 5);         // 4 floats, stride 32 across k
            float4 v = *(const float4*)(xp + c);
            uint2 pk;
            pk.x = f2bf2(v.x, v.y);
            pk.y = f2bf2(v.z, v.w);
            *(uint2*)&smem[OFF_X + t * 208 + c] = pk;
        }
    }

    // hoist first phase-1 B fragment (global only, overlaps barrier drain)
    int nb = wv;
    float bias = bq[nb * 16 + l15];
    bf16x8 bfr[6];
    {
        const unsigned short* wp = WqT + (nb * 16 + l15) * 192 + g * 8;
#pragma unroll
        for (int kk = 0; kk < 6; ++kk) bfr[kk] = *(const bf16x8*)(wp + kk * 32);
    }
    __syncthreads();

    // ---------- phase 1: QKV = Xw(64x192) @ WqT^T + bq  (64x576) ----------
    {
        bf16x8 afr[4][6];          // A fragments cached: 4 m-blocks x 6 k-iters
#pragma unroll
        for (int m = 0; m < 4; ++m)
#pragma unroll
            for (int kk = 0; kk < 6; ++kk)
                afr[m][kk] = *(const bf16x8*)&smem[OFF_X + (m * 16 + l15) * 208 + kk * 32 + g * 8];

        while (true) {
            int nbN = nb + 8;
            bool more = (nbN < 36);
            bf16x8 bfrN[6];
            float biasN = 0.f;
            if (more) {
                biasN = bq[nbN * 16 + l15];
                const unsigned short* wp = WqT + (nbN * 16 + l15) * 192 + g * 8;
#pragma unroll
                for (int kk = 0; kk < 6; ++kk) bfrN[kk] = *(const bf16x8*)(wp + kk * 32);
            }
            int colg = nb * 16 + l15;
            bool isV = (nb >= 24);
#pragma unroll
            for (int m = 0; m < 4; ++m) {
                f32x4 acc = {bias, bias, bias, bias};
#pragma unroll
                for (int kk = 0; kk < 6; ++kk) acc = MFMA16(afr[m][kk], bfr[kk], acc);
                int row0 = m * 16 + g * 4;
                unsigned int u01 = f2bf2(acc[0], acc[1]);
                unsigned int u23 = f2bf2(acc[2], acc[3]);
                if (!isV) {                       // Q/K -> sQK[t][col]
                    unsigned short* qk = &smem[OFF_QK + row0 * 392 + colg];
                    qk[0]    = (unsigned short)u01;
                    qk[392]  = (unsigned short)(u01 >> 16);
                    qk[784]  = (unsigned short)u23;
                    qk[1176] = (unsigned short)(u23 >> 16);
                } else {                          // V -> sVt[c][t], 4 contiguous t
                    uint2 pk; pk.x = u01; pk.y = u23;
                    *(uint2*)&smem[OFF_VT + (colg - 384) * 72 + row0] = pk;
                }
            }
            if (!more) break;
            nb = nbN;
            bias = biasN;
#pragma unroll
            for (int kk = 0; kk < 6; ++kk) bfr[kk] = bfrN[kk];
        }
    }
    __syncthreads();

    // ---------- phase 2: per (head, 16-row block) attention ----------
    const bool sz = (wz == 7), sy = (wy == 7), sx = (wx == 7);
    {
        const int qy = (l15 >> 2) & 3, qx = l15 & 3;
        unsigned short* pb = &smem[OFF_P + wv * 1152];
        for (int it = wv * 3; it < wv * 3 + 3; ++it) {
            int h = it >> 2, mb = it & 3;
            bf16x8 qf = *(const bf16x8*)&smem[OFF_QK + (mb * 16 + l15) * 392 + h * 32 + g * 8];
            f32x4 s[4];
#pragma unroll
            for (int f = 0; f < 4; ++f) {
                bf16x8 kf = *(const bf16x8*)&smem[OFF_QK + (f * 16 + l15) * 392 + 192 + h * 32 + g * 8];
                f32x4 z = {0.f, 0.f, 0.f, 0.f};
                s[f] = MFMA16(qf, kf, z);
            }
            // bias + shift mask + exp2 (log2 domain; masked -> exp2(-1e30)=0)
#pragma unroll
            for (int f = 0; f < 4; ++f) {
                bool mz = sz && ((mb < 2) != (f < 2));
                bool my = sy && ((g < 2) != (qy < 2));
                int base = h * 343 + (mb - f + 3) * 49 + (g - qy + 3) * 7 + (3 - qx);
#pragma unroll
                for (int r = 0; r < 4; ++r) {
                    float v = s[f][r] + sRel[base + r];
                    bool mx = sx && ((r < 2) != (qx < 2));
                    v = (mz | my | mx) ? -1e30f : v;
                    s[f][r] = exp2f(v);
                }
            }
            // row sums via DPP (row = 16 lanes of this g-group); P stays unnormalized
            float inv[4];
#pragma unroll
            for (int r = 0; r < 4; ++r) {
                float sm = (s[0][r] + s[1][r]) + (s[2][r] + s[3][r]);
                DPPADD(sm, 0xB1);    // quad_perm [1,0,3,2]
                DPPADD(sm, 0x4E);    // quad_perm [2,3,0,1]
                DPPADD(sm, 0x124);   // row_ror:4
                DPPADD(sm, 0x128);   // row_ror:8
                inv[r] = __builtin_amdgcn_rcpf(sm);
            }
            // P (C-layout) -> per-wave LDS -> A-frags (same wave, no barrier)
#pragma unroll
            for (int f = 0; f < 4; ++f) {
                unsigned int u01 = f2bf2(s[f][0], s[f][1]);
                unsigned int u23 = f2bf2(s[f][2], s[f][3]);
                unsigned short* pw = &pb[(g * 4) * 72 + f * 16 + l15];
                pw[0]   = (unsigned short)u01;
                pw[72]  = (unsigned short)(u01 >> 16);
                pw[144] = (unsigned short)u23;
                pw[216] = (unsigned short)(u23 >> 16);
            }
            // PV: O(16x32) = P(16x64) @ V(64x32), then normalize by inv[r]
            f32x4 o0 = {0.f, 0.f, 0.f, 0.f}, o1 = {0.f, 0.f, 0.f, 0.f};
#pragma unroll
            for (int kt = 0; kt < 2; ++kt) {
                bf16x8 pf = *(const bf16x8*)&pb[l15 * 72 + kt * 32 + g * 8];
                bf16x8 v0 = *(const bf16x8*)&smem[OFF_VT + (h * 32 + l15) * 72 + kt * 32 + g * 8];
                bf16x8 v1 = *(const bf16x8*)&smem[OFF_VT + (h * 32 + 16 + l15) * 72 + kt * 32 + g * 8];
                o0 = MFMA16(pf, v0, o0);
                o1 = MFMA16(pf, v1, o1);
            }
#pragma unroll
            for (int r = 0; r < 4; ++r) { o0[r] *= inv[r]; o1[r] *= inv[r]; }
            unsigned int a0 = f2bf2(o0[0], o0[1]), a1 = f2bf2(o0[2], o0[3]);
            unsigned int c0 = f2bf2(o1[0], o1[1]), c1 = f2bf2(o1[2], o1[3]);
            unsigned short* ow = &smem[OFF_O + (mb * 16 + g * 4) * 208 + h * 32 + l15];
            ow[0]        = (unsigned short)a0;
            ow[208]      = (unsigned short)(a0 >> 16);
            ow[416]      = (unsigned short)a1;
            ow[624]      = (unsigned short)(a1 >> 16);
            ow[16]       = (unsigned short)c0;
            ow[16 + 208] = (unsigned short)(c0 >> 16);
            ow[16 + 416] = (unsigned short)c1;
            ow[16 + 624] = (unsigned short)(c1 >> 16);
        }
    }

    // hoist first phase-3 B fragment + bias (global only, overlaps barrier drain)
    const int mw = wv >> 2, nq = wv & 3;
    int col0 = nq * 16 + l15;
    float bo0 = bout[col0];
    bf16x8 bfr0[6];
    {
        const unsigned short* wp = WoT + col0 * 192 + g * 8;
#pragma unroll
        for (int kk = 0; kk < 6; ++kk) bfr0[kk] = *(const bf16x8*)(wp + kk * 32);
    }
    __syncthreads();

    // ---------- phase 3: out = O(64x192) @ WoT^T + b_out, scatter to global ----------
    {
        bf16x8 ofr[2][6];
#pragma unroll
        for (int mi = 0; mi < 2; ++mi)
#pragma unroll
            for (int kk = 0; kk < 6; ++kk)
                ofr[mi][kk] = *(const bf16x8*)&smem[OFF_O + ((mw * 2 + mi) * 16 + l15) * 208 + kk * 32 + g * 8];
#pragma unroll
        for (int nbi = 0; nbi < 3; ++nbi) {
            int col = (nq + nbi * 4) * 16 + l15;
            float bo;
            bf16x8 bfr[6];
            if (nbi == 0) {
                bo = bo0;
#pragma unroll
                for (int kk = 0; kk < 6; ++kk) bfr[kk] = bfr0[kk];
            } else {
                bo = bout[col];
                const unsigned short* wp = WoT + col * 192 + g * 8;
#pragma unroll
                for (int kk = 0; kk < 6; ++kk) bfr[kk] = *(const bf16x8*)(wp + kk * 32);
            }
#pragma unroll
            for (int mi = 0; mi < 2; ++mi) {
                f32x4 acc = {bo, bo, bo, bo};
#pragma unroll
                for (int kk = 0; kk < 6; ++kk) acc = MFMA16(ofr[mi][kk], bfr[kk], acc);
                int m = mw * 2 + mi;                    // token t = m*16 + g*4 + r
                int gz = (wz * 4 + m + 2) & 31;         // roll(+2) folded in
                int gy = (wy * 4 + g + 2) & 31;
#pragma unroll
                for (int r = 0; r < 4; ++r) {
                    int gx = (wx * 4 + r + 2) & 31;
                    out[(((b * 32 + gz) * 32 + gy) * 32 + gx) * 192 + col] = acc[r];
                }
            }
        }
    }
}

extern "C" void kernel_launch(void* const* d_in, const int* in_sizes, int n_in,
                              void* d_out, int out_size, void* d_ws, size_t ws_size,
                              hipStream_t stream) {
    const float* x    = (const float*)d_in[0];
    const float* Wqkv = (const float*)d_in[1];
    const float* bqkv = (const float*)d_in[2];
    const float* rel  = (const float*)d_in[3];
    const float* Wout = (const float*)d_in[4];
    const float* bout = (const float*)d_in[5];

    unsigned short* WqT = (unsigned short*)((char*)d_ws + WQT_OFF);
    unsigned short* WoT = (unsigned short*)((char*)d_ws + WOT_OFF);
    float*          bq  = (float*)((char*)d_ws + BQ_OFF);
    float*          out = (float*)d_out;

    prep_kernel<<<145, 256, 0, stream>>>(Wqkv, bqkv, Wout, WqT, WoT, bq);
    wmsa_kernel<<<1024, 512, 0, stream>>>(x, rel, bout, WqT, WoT, bq, out);
}